// Round 1
// baseline (36.722 us; speedup 1.0000x reference)
//
#include <hip/hip_runtime.h>

#define BATCH 64
#define IMH 256
#define IMW 256
#define CIN 512
#define NH 128

// Kernel 1: per-batch MLP -> alpha + 9 sigmoid kernel weights.
// One block per batch element, 128 threads (= N_HIDDEN).
__global__ void mlp_kernel(const float* __restrict__ features,
                           const float* __restrict__ W0, const float* __restrict__ b0,
                           const float* __restrict__ W1, const float* __restrict__ b1,
                           const float* __restrict__ W2, const float* __restrict__ b2,
                           float* __restrict__ ak /* [BATCH][10] */) {
    const int b = blockIdx.x;
    const int t = threadIdx.x;  // 0..127

    __shared__ float f[CIN];
    __shared__ float h0[NH];
    __shared__ float h1[NH];

    for (int i = t; i < CIN; i += NH) f[i] = features[b * CIN + i];
    __syncthreads();

    // layer 0: h0[t] = relu(dot(f, W0[t,:]) + b0[t])
    {
        const float* w = W0 + t * CIN;
        float a0 = 0.f, a1 = 0.f, a2 = 0.f, a3 = 0.f;
        #pragma unroll 4
        for (int i = 0; i < CIN; i += 4) {
            a0 = fmaf(f[i + 0], w[i + 0], a0);
            a1 = fmaf(f[i + 1], w[i + 1], a1);
            a2 = fmaf(f[i + 2], w[i + 2], a2);
            a3 = fmaf(f[i + 3], w[i + 3], a3);
        }
        h0[t] = fmaxf(b0[t] + ((a0 + a1) + (a2 + a3)), 0.f);
    }
    __syncthreads();

    // layer 1: h1[t] = relu(dot(h0, W1[t,:]) + b1[t])
    {
        const float* w = W1 + t * NH;
        float a0 = 0.f, a1 = 0.f, a2 = 0.f, a3 = 0.f;
        #pragma unroll 4
        for (int i = 0; i < NH; i += 4) {
            a0 = fmaf(h0[i + 0], w[i + 0], a0);
            a1 = fmaf(h0[i + 1], w[i + 1], a1);
            a2 = fmaf(h0[i + 2], w[i + 2], a2);
            a3 = fmaf(h0[i + 3], w[i + 3], a3);
        }
        h1[t] = fmaxf(b1[t] + ((a0 + a1) + (a2 + a3)), 0.f);
    }
    __syncthreads();

    // layer 2: beta (10 outputs) + identity bias; alpha = beta[0], kern = sigmoid(beta[1:])
    if (t < 10) {
        const float* w = W2 + t * NH;
        float a0 = 0.f, a1 = 0.f, a2 = 0.f, a3 = 0.f;
        #pragma unroll 4
        for (int i = 0; i < NH; i += 4) {
            a0 = fmaf(h1[i + 0], w[i + 0], a0);
            a1 = fmaf(h1[i + 1], w[i + 1], a1);
            a2 = fmaf(h1[i + 2], w[i + 2], a2);
            a3 = fmaf(h1[i + 3], w[i + 3], a3);
        }
        float beta = b2[t] + ((a0 + a1) + (a2 + a3));
        float outv;
        if (t == 0) {
            outv = beta;  // alpha (identity bias contributes 0)
        } else {
            beta += (t == 5) ? 5.f : -5.f;   // identity bias: center tap +5, others -5
            outv = 1.f / (1.f + expf(-beta)); // sigmoid
        }
        ak[b * 10 + t] = outv;
    }
}

// Kernel 2: 3x3 smooth-max pooling with per-batch alpha/kernel.
// grid = (IMH, BATCH), block = IMW threads; 1 thread = 1 output pixel.
__global__ void smoothmax_kernel(const float* __restrict__ x,
                                 const float* __restrict__ ak,
                                 float* __restrict__ out) {
    const int w = threadIdx.x;   // 0..255
    const int h = blockIdx.x;    // 0..255
    const int b = blockIdx.y;    // 0..63

    const float* akb = ak + b * 10;
    const float alpha = akb[0];
    float kern[9];
    #pragma unroll
    for (int i = 0; i < 9; ++i) kern[i] = akb[1 + i];

    const float* xb = x + (size_t)b * (IMH * IMW);

    float num = 0.f, den = 0.f;
    #pragma unroll
    for (int dy = -1; dy <= 1; ++dy) {
        const int hh = h + dy;
        const bool rowok = ((unsigned)hh < (unsigned)IMH);
        #pragma unroll
        for (int dx = -1; dx <= 1; ++dx) {
            const int ww = w + dx;
            const bool ok = rowok && ((unsigned)ww < (unsigned)IMW);
            // zero-padded patch: OOB contributes p=0 but still weight kern_k
            const float p = ok ? xb[hh * IMW + ww] : 0.f;
            const int ki = (dy + 1) * 3 + (dx + 1);
            const float wt = __expf(alpha * p) * kern[ki];
            num = fmaf(p, wt, num);
            den += wt;
        }
    }
    out[(size_t)b * (IMH * IMW) + h * IMW + w] = num / den;
}

extern "C" void kernel_launch(void* const* d_in, const int* in_sizes, int n_in,
                              void* d_out, int out_size, void* d_ws, size_t ws_size,
                              hipStream_t stream) {
    const float* x        = (const float*)d_in[0];
    const float* features = (const float*)d_in[1];
    const float* W0       = (const float*)d_in[2];
    const float* b0       = (const float*)d_in[3];
    const float* W1       = (const float*)d_in[4];
    const float* b1       = (const float*)d_in[5];
    const float* W2       = (const float*)d_in[6];
    const float* b2       = (const float*)d_in[7];
    float* out = (float*)d_out;
    float* ak  = (float*)d_ws;  // BATCH*10 floats

    mlp_kernel<<<BATCH, NH, 0, stream>>>(features, W0, b0, W1, b1, W2, b2, ak);
    smoothmax_kernel<<<dim3(IMH, BATCH), IMW, 0, stream>>>(x, ak, out);
}